// Round 1
// baseline (115.459 us; speedup 1.0000x reference)
//
#include <hip/hip_runtime.h>

// LowRankBilinearPooling: out[b,o] = (sum_i relu(x1 W1))_h * (sum_j relu(x2 W2))_h @ Wp + bp*196^2
// B=16, N=196, C=768, H=512, O=128. All fp32 in/out; internally bf16 MFMA.

#define NB 16
#define NROW 196
#define KC_ 768
#define HH 512
#define OO 128

using short8 = __attribute__((ext_vector_type(8))) short;
using f32x16 = __attribute__((ext_vector_type(16))) float;

__device__ __forceinline__ unsigned short f2bf(float f) {
    union { float f; unsigned u; } c; c.f = f;
    unsigned u = c.u;
    u += 0x7fffu + ((u >> 16) & 1u);   // RNE
    return (unsigned short)(u >> 16);
}

// Kernel 1: fused GEMM + relu + row-sum.
// Grid: 256 blocks = 2(branch) x 16(b) x 4(ht: 128-col tile) x 2(mh: 128-row half).
// Block: 256 threads = 4 waves; wave w: strip-pair sp=w&1 (cols sp*64..sp*64+63),
// M-pair mp=w>>1 (32-row tiles 2mp, 2mp+1 of this WG's 4 slots).
// sbuf layout: [branch(2)][mh(2)][b(16)][h(512)] float.
__global__ __launch_bounds__(256, 1)
void gemm_relu_rowsum(const float* __restrict__ x1, const float* __restrict__ x2,
                      const float* __restrict__ W1, const float* __restrict__ W2,
                      float* __restrict__ sbuf) {
    // LDS: A[k8(8)][row(128)][8] bf16, B[k8(8)][col(128)][8] bf16 (16 KB each)
    __shared__ unsigned short Alds[8 * 128 * 8];
    __shared__ unsigned short Blds[8 * 128 * 8];
    __shared__ float psum[4 * 2 * 32];

    const int bid = blockIdx.x;
    const int p  = bid & 31;          // (branch,b) -> same XCD for all its tiles
    const int tt = bid >> 5;          // 0..7
    const int branch = p >> 4;
    const int b      = p & 15;
    const int ht = tt >> 1;           // 0..3
    const int mh = tt & 1;            // 0..1
    const int c0 = ht * 128;

    const float* __restrict__ x = branch ? x2 : x1;
    const float* __restrict__ W = branch ? W2 : W1;

    const int t  = threadIdx.x;
    const int w  = t >> 6;
    const int l  = t & 63;
    const int rn = t & 127;           // A-row / B-col owned by this thread (staging)
    const int gh = t >> 7;            // 0/1: which k8-group parity

    const int r_abs = mh * 128 + rn;
    const bool valid = r_abs < NROW;
    const float* xrow = x + (b * NROW + (valid ? r_abs : 0)) * KC_;
    const float* Wcol = W + c0 + rn;

    float4 alo[4], ahi[4];
    float  bv[4][8];

    auto load_stage = [&](int kc) {
        const int k0 = kc * 64;
#pragma unroll
        for (int gi = 0; gi < 4; ++gi) {
            const int g = gh + 2 * gi;          // k8 group 0..7
            if (valid) {
                alo[gi] = *(const float4*)(xrow + k0 + g * 8);
                ahi[gi] = *(const float4*)(xrow + k0 + g * 8 + 4);
            } else {
                alo[gi] = make_float4(0.f, 0.f, 0.f, 0.f);
                ahi[gi] = make_float4(0.f, 0.f, 0.f, 0.f);
            }
#pragma unroll
            for (int j = 0; j < 8; ++j)
                bv[gi][j] = Wcol[(k0 + g * 8 + j) * HH];
        }
    };

    auto write_stage = [&]() {
#pragma unroll
        for (int gi = 0; gi < 4; ++gi) {
            const int g = gh + 2 * gi;
            short8 av, bw;
            av[0] = (short)f2bf(alo[gi].x); av[1] = (short)f2bf(alo[gi].y);
            av[2] = (short)f2bf(alo[gi].z); av[3] = (short)f2bf(alo[gi].w);
            av[4] = (short)f2bf(ahi[gi].x); av[5] = (short)f2bf(ahi[gi].y);
            av[6] = (short)f2bf(ahi[gi].z); av[7] = (short)f2bf(ahi[gi].w);
#pragma unroll
            for (int j = 0; j < 8; ++j) bw[j] = (short)f2bf(bv[gi][j]);
            *(short8*)&Alds[g * 1024 + rn * 8] = av;
            *(short8*)&Blds[g * 1024 + rn * 8] = bw;
        }
    };

    const int m  = l & 31;
    const int q  = l >> 5;
    const int sp = w & 1;
    const int mp = w >> 1;
    const int aoff = (mp * 64 + m) * 8;   // slot 2mp, row m
    const int boff = (sp * 64 + m) * 8;   // strip 2sp, col m

    f32x16 acc00 = {}, acc01 = {}, acc10 = {}, acc11 = {};

    load_stage(0);
#pragma unroll 1
    for (int kc = 0; kc < 12; ++kc) {
        __syncthreads();                  // prior MFMA phase done reading LDS
        write_stage();
        __syncthreads();
        if (kc < 11) load_stage(kc + 1);  // overlap next chunk's loads with MFMA
#pragma unroll
        for (int ks = 0; ks < 4; ++ks) {
            const int base = (ks * 2 + q) * 1024;
            short8 a0 = *(const short8*)&Alds[base + aoff];
            short8 a1 = *(const short8*)&Alds[base + aoff + 256];
            short8 b0 = *(const short8*)&Blds[base + boff];
            short8 b1 = *(const short8*)&Blds[base + boff + 256];
            acc00 = __builtin_amdgcn_mfma_f32_32x32x16_bf16(a0, b0, acc00, 0, 0, 0);
            acc01 = __builtin_amdgcn_mfma_f32_32x32x16_bf16(a0, b1, acc01, 0, 0, 0);
            acc10 = __builtin_amdgcn_mfma_f32_32x32x16_bf16(a1, b0, acc10, 0, 0, 0);
            acc11 = __builtin_amdgcn_mfma_f32_32x32x16_bf16(a1, b1, acc11, 0, 0, 0);
        }
    }

    // relu + sum over all rows. C layout: col = lane&31 (m101-verified); rows are
    // fully covered by the 16 regs of lanes l and l^32 together, order irrelevant.
    float cs0 = 0.f, cs1 = 0.f;
#pragma unroll
    for (int r = 0; r < 16; ++r) {
        cs0 += fmaxf(acc00[r], 0.f) + fmaxf(acc10[r], 0.f);
        cs1 += fmaxf(acc01[r], 0.f) + fmaxf(acc11[r], 0.f);
    }
    cs0 += __shfl_xor(cs0, 32);
    cs1 += __shfl_xor(cs1, 32);
    if (l < 32) {
        psum[(w * 2 + 0) * 32 + l] = cs0;
        psum[(w * 2 + 1) * 32 + l] = cs1;
    }
    __syncthreads();
    if (t < 128) {
        const int sg = t >> 5;            // global strip 0..3
        const int cl = t & 31;
        const int sp2 = sg >> 1, st = sg & 1;
        const float v = psum[((sp2 + 0) * 2 + st) * 32 + cl]
                      + psum[((sp2 + 2) * 2 + st) * 32 + cl];
        sbuf[((branch * 2 + mh) * NB + b) * HH + c0 + t] = v;
    }
}

// Kernel 2: out[b,o] = sum_h (s1[b,h]*s2[b,h]) * Wp[h,o] + bp[o]*196^2
__global__ __launch_bounds__(128)
void proj_kernel(const float* __restrict__ sbuf, const float* __restrict__ Wp,
                 const float* __restrict__ bp, float* __restrict__ out) {
    __shared__ float spl[HH];
    const int b = blockIdx.x, t = threadIdx.x;
#pragma unroll
    for (int i = 0; i < 4; ++i) {
        const int h = t + i * 128;
        const float s1 = sbuf[(0 * NB + b) * HH + h] + sbuf[(1 * NB + b) * HH + h];
        const float s2 = sbuf[(2 * NB + b) * HH + h] + sbuf[(3 * NB + b) * HH + h];
        spl[h] = s1 * s2;
    }
    __syncthreads();
    float acc = 0.f;
#pragma unroll 8
    for (int h = 0; h < HH; ++h)
        acc += spl[h] * Wp[h * OO + t];
    out[b * OO + t] = acc + bp[t] * 38416.0f;   // 196*196
}

extern "C" void kernel_launch(void* const* d_in, const int* in_sizes, int n_in,
                              void* d_out, int out_size, void* d_ws, size_t ws_size,
                              hipStream_t stream) {
    const float* x1 = (const float*)d_in[0];
    const float* x2 = (const float*)d_in[1];
    const float* W1 = (const float*)d_in[2];
    const float* W2 = (const float*)d_in[3];
    const float* Wp = (const float*)d_in[4];
    const float* bp = (const float*)d_in[5];
    float* sbuf = (float*)d_ws;                 // 2*2*16*512 floats = 128 KB

    gemm_relu_rowsum<<<256, 256, 0, stream>>>(x1, x2, W1, W2, sbuf);
    proj_kernel<<<16, 128, 0, stream>>>(sbuf, Wp, bp, (float*)d_out);
}

// Round 2
// 100.909 us; speedup vs baseline: 1.1442x; 1.1442x over previous
//
#include <hip/hip_runtime.h>
#include <hip/hip_bf16.h>

// LowRankBilinearPooling: out[b,o] = (sum_i relu(x1 W1))_h * (sum_j relu(x2 W2))_h @ Wp + bp*196^2
// B=16, N=196, C=768, H=512, O=128. fp32 in/out; bf16 MFMA inside.

#define NB 16
#define NROW 196
#define KC_ 768
#define HH 512
#define OO 128

using short8 = __attribute__((ext_vector_type(8))) short;
using f32x16 = __attribute__((ext_vector_type(16))) float;

__device__ __forceinline__ short2 pk2bf(float a, float b) {
    // lowers to v_cvt_pk_bf16_f32 on gfx950 (1 op / 2 elems)
    __hip_bfloat162 h = __float22bfloat162_rn(make_float2(a, b));
    union { __hip_bfloat162 h; short2 s; } u; u.h = h;
    return u.s;
}

// Kernel 1: fused GEMM + relu + row-sum.
// Grid: 256 blocks = 2(branch) x 16(b) x 4(ht: 128-col tile) x 2(mh: 128-row half).
// Block: 512 threads = 8 waves = (mp 0..3: 32-row tile) x (sp 0..1: 64-col strip).
// K chunked by 64; double-buffered LDS, ONE barrier per chunk.
__global__ __launch_bounds__(512, 1)
void gemm_relu_rowsum(const float* __restrict__ x1, const float* __restrict__ x2,
                      const float* __restrict__ W1, const float* __restrict__ W2,
                      float* __restrict__ sbuf) {
    // [buf][k8(8)][row/col(128)][8] bf16 : 16 KB each plane, 64 KB total
    __shared__ unsigned short Alds[2][8 * 128 * 8];
    __shared__ unsigned short Blds[2][8 * 128 * 8];
    __shared__ float psum[16 * 32];

    const int bid = blockIdx.x;
    const int p  = bid & 31;           // (branch,b): tiles of same x[b] share an XCD
    const int tt = bid >> 5;
    const int branch = p >> 4;
    const int b      = p & 15;
    const int ht = tt >> 1;
    const int mh = tt & 1;
    const int c0 = ht * 128;

    const float* __restrict__ x = branch ? x2 : x1;
    const float* __restrict__ W = branch ? W2 : W1;

    const int t  = threadIdx.x;
    const int rn = t & 127;            // staging row (A) / col (B)
    const int kg = t >> 7;             // 0..3: which 16-k slice of the 64-k chunk

    const int r_abs = mh * 128 + rn;
    const bool valid = r_abs < NROW;
    const float* xrow  = x + (b * NROW + (valid ? r_abs : 0)) * KC_ + kg * 16;
    const float* Wbase = W + c0 + rn;

    float4 av[4];      // 16 consecutive k of one A row (one 64B line)
    float  bv[2][8];   // two (col, k8) units of B

    auto load_stage = [&](int kc) {
        const int k0 = kc * 64;
        if (valid) {
#pragma unroll
            for (int i = 0; i < 4; ++i)
                av[i] = *(const float4*)(xrow + k0 + 4 * i);
        } else {
#pragma unroll
            for (int i = 0; i < 4; ++i) av[i] = make_float4(0.f, 0.f, 0.f, 0.f);
        }
#pragma unroll
        for (int u = 0; u < 2; ++u)
#pragma unroll
            for (int j = 0; j < 8; ++j)
                bv[u][j] = Wbase[(k0 + (kg + 4 * u) * 8 + j) * HH];
    };

    auto write_stage = [&](int buf) {
        short8 w0, w1, y0, y1;
        short2 s;
        s = pk2bf(av[0].x, av[0].y); w0[0] = s.x; w0[1] = s.y;
        s = pk2bf(av[0].z, av[0].w); w0[2] = s.x; w0[3] = s.y;
        s = pk2bf(av[1].x, av[1].y); w0[4] = s.x; w0[5] = s.y;
        s = pk2bf(av[1].z, av[1].w); w0[6] = s.x; w0[7] = s.y;
        s = pk2bf(av[2].x, av[2].y); w1[0] = s.x; w1[1] = s.y;
        s = pk2bf(av[2].z, av[2].w); w1[2] = s.x; w1[3] = s.y;
        s = pk2bf(av[3].x, av[3].y); w1[4] = s.x; w1[5] = s.y;
        s = pk2bf(av[3].z, av[3].w); w1[6] = s.x; w1[7] = s.y;
#pragma unroll
        for (int j = 0; j < 4; ++j) {
            s = pk2bf(bv[0][2 * j], bv[0][2 * j + 1]); y0[2 * j] = s.x; y0[2 * j + 1] = s.y;
            s = pk2bf(bv[1][2 * j], bv[1][2 * j + 1]); y1[2 * j] = s.x; y1[2 * j + 1] = s.y;
        }
        *(short8*)&Alds[buf][((2 * kg + 0) * 128 + rn) * 8] = w0;  // k kg*16..+7
        *(short8*)&Alds[buf][((2 * kg + 1) * 128 + rn) * 8] = w1;  // k kg*16+8..+15
        *(short8*)&Blds[buf][((kg + 0) * 128 + rn) * 8] = y0;      // k8 group kg
        *(short8*)&Blds[buf][((kg + 4) * 128 + rn) * 8] = y1;      // k8 group kg+4
    };

    const int w  = t >> 6;
    const int l  = t & 63;
    const int m  = l & 31;
    const int q  = l >> 5;
    const int sp = w & 1;              // 64-col strip
    const int mp = w >> 1;             // 32-row tile
    const int aoff = (mp * 32 + m) * 8;
    const int boff = (sp * 64 + m) * 8;

    f32x16 acc0 = {}, acc1 = {};

    load_stage(0);
    write_stage(0);
    load_stage(1);
    __syncthreads();

#pragma unroll 1
    for (int kc = 0; kc < 12; ++kc) {
        const int pb = kc & 1;
#pragma unroll
        for (int ks = 0; ks < 4; ++ks) {
            const int base = (ks * 2 + q) * 1024;
            short8 af = *(const short8*)&Alds[pb][base + aoff];
            short8 b0 = *(const short8*)&Blds[pb][base + boff];
            short8 b1 = *(const short8*)&Blds[pb][base + boff + 256];
            acc0 = __builtin_amdgcn_mfma_f32_32x32x16_bf16(af, b0, acc0, 0, 0, 0);
            acc1 = __builtin_amdgcn_mfma_f32_32x32x16_bf16(af, b1, acc1, 0, 0, 0);
        }
        if (kc < 11) write_stage(1 - pb);   // chunk kc+1 -> other buffer (no race w/ mfma)
        if (kc < 10) load_stage(kc + 2);    // stays in flight across next chunk's mfma
        __syncthreads();                    // one barrier per chunk
    }

    // relu + sum over rows. C layout: col = lane&31 (m101); lanes l and l^32's
    // 16 regs together cover all 32 rows, order irrelevant for a sum.
    float cs0 = 0.f, cs1 = 0.f;
#pragma unroll
    for (int r = 0; r < 16; ++r) {
        cs0 += fmaxf(acc0[r], 0.f);
        cs1 += fmaxf(acc1[r], 0.f);
    }
    cs0 += __shfl_xor(cs0, 32);
    cs1 += __shfl_xor(cs1, 32);
    if (l < 32) {
        psum[((sp * 2 + 0) * 4 + mp) * 32 + l] = cs0;  // col tile 2sp
        psum[((sp * 2 + 1) * 4 + mp) * 32 + l] = cs1;  // col tile 2sp+1
    }
    __syncthreads();
    if (t < 128) {
        const int ct = t >> 5;
        const int cl = t & 31;
        float v = 0.f;
#pragma unroll
        for (int mp2 = 0; mp2 < 4; ++mp2)
            v += psum[(ct * 4 + mp2) * 32 + cl];
        sbuf[((branch * 2 + mh) * NB + b) * HH + c0 + t] = v;
    }
}

// Kernel 2: out[b,o] = sum_h (s1[b,h]*s2[b,h]) * Wp[h,o] + bp[o]*196^2
__global__ __launch_bounds__(512)
void proj_kernel(const float* __restrict__ sbuf, const float* __restrict__ Wp,
                 const float* __restrict__ bp, float* __restrict__ out) {
    __shared__ float spl[HH];
    __shared__ float red[4][OO];
    const int b = blockIdx.x, t = threadIdx.x;
    {
        const float s1 = sbuf[(0 * NB + b) * HH + t] + sbuf[(1 * NB + b) * HH + t];
        const float s2 = sbuf[(2 * NB + b) * HH + t] + sbuf[(3 * NB + b) * HH + t];
        spl[t] = s1 * s2;
    }
    __syncthreads();
    const int to = t & 127, hq = t >> 7;
    float acc = 0.f;
#pragma unroll 8
    for (int h = hq * 128; h < hq * 128 + 128; ++h)
        acc += spl[h] * Wp[h * OO + to];
    red[hq][to] = acc;
    __syncthreads();
    if (t < OO)
        out[b * OO + t] = red[0][t] + red[1][t] + red[2][t] + red[3][t]
                        + bp[t] * 38416.0f;   // 196*196
}

extern "C" void kernel_launch(void* const* d_in, const int* in_sizes, int n_in,
                              void* d_out, int out_size, void* d_ws, size_t ws_size,
                              hipStream_t stream) {
    const float* x1 = (const float*)d_in[0];
    const float* x2 = (const float*)d_in[1];
    const float* W1 = (const float*)d_in[2];
    const float* W2 = (const float*)d_in[3];
    const float* Wp = (const float*)d_in[4];
    const float* bp = (const float*)d_in[5];
    float* sbuf = (float*)d_ws;                 // 2*2*16*512 floats = 128 KB

    gemm_relu_rowsum<<<256, 512, 0, stream>>>(x1, x2, W1, W2, sbuf);
    proj_kernel<<<NB, 512, 0, stream>>>(sbuf, Wp, bp, (float*)d_out);
}

// Round 3
// 94.075 us; speedup vs baseline: 1.2273x; 1.0726x over previous
//
#include <hip/hip_runtime.h>
#include <hip/hip_bf16.h>

// LowRankBilinearPooling: out[b,o] = (sum_i relu(x1 W1))_h * (sum_j relu(x2 W2))_h @ Wp + bp*196^2
// B=16, N=196, C=768, H=512, O=128. fp32 in/out; bf16 MFMA inside.

#define NB 16
#define NROW 196
#define KC_ 768
#define HH 512
#define OO 128

using short4v = __attribute__((ext_vector_type(4))) short;
using short8 = __attribute__((ext_vector_type(8))) short;
using f32x16 = __attribute__((ext_vector_type(16))) float;

__device__ __forceinline__ short2 pk2bf(float a, float b) {
    // lowers to v_cvt_pk_bf16_f32 on gfx950 (1 op / 2 elems)
    __hip_bfloat162 h = __float22bfloat162_rn(make_float2(a, b));
    union { __hip_bfloat162 h; short2 s; } u; u.h = h;
    return u.s;
}

// Prepass: tile+convert W1/W2 into the gemm's exact LDS byte order, bf16.
// Wt[(branch*4+ht)*12+kc][p(8)][col(128)][8] : unit (p,col) = bf16 of
// W[(kc*64+p*8+j)*512 + ht*128 + col], j=0..7.  96 blocks x 256 threads.
__global__ __launch_bounds__(256)
void w_tile(const float* __restrict__ W1, const float* __restrict__ W2,
            unsigned short* __restrict__ Wt) {
    const int bb = blockIdx.x;              // branch*48 + ht*12 + kc
    const int branch = bb / 48;
    const int rem = bb % 48;
    const int ht = rem / 12;
    const int kc = rem % 12;
    const float* __restrict__ W = branch ? W2 : W1;
    unsigned short* __restrict__ out = Wt + (size_t)bb * 8192;
    const int t = threadIdx.x;
#pragma unroll
    for (int i = 0; i < 4; ++i) {
        const int u = i * 256 + t;
        const int p = u >> 7, col = u & 127;
        const float* src = W + (kc * 64 + p * 8) * HH + ht * 128 + col;
        float f[8];
#pragma unroll
        for (int j = 0; j < 8; ++j) f[j] = src[j * HH];   // lanes walk col: coalesced
        short8 v; short2 s;
#pragma unroll
        for (int j = 0; j < 4; ++j) {
            s = pk2bf(f[2 * j], f[2 * j + 1]); v[2 * j] = s.x; v[2 * j + 1] = s.y;
        }
        *(short8*)(out + u * 8) = v;                      // contiguous store
    }
}

// Kernel 1: fused GEMM + relu + row-sum.
// Grid: 256 blocks = 2(branch) x 16(b) x 4(ht) x 2(mh). Block: 512 thr = 8 waves
// = (mp 0..3: 32-row tile) x (sp 0..1: 64-col strip). K chunked by 64,
// double-buffered LDS, one barrier per chunk. LDS plane stride 129 units (pad).
__global__ __launch_bounds__(512, 1)
void gemm_relu_rowsum(const float* __restrict__ x1, const float* __restrict__ x2,
                      const unsigned short* __restrict__ Wt,
                      float* __restrict__ sbuf) {
    __shared__ unsigned short Alds[2][8 * 129 * 8];
    __shared__ unsigned short Blds[2][8 * 129 * 8];
    __shared__ float psum[16 * 32];

    const int bid = blockIdx.x;
    const int p  = bid & 31;           // (branch,b): tiles of same x[b] share an XCD
    const int tt = bid >> 5;
    const int branch = p >> 4;
    const int b      = p & 15;
    const int ht = tt >> 1;
    const int mh = tt & 1;

    const float* __restrict__ x = branch ? x2 : x1;
    const unsigned short* __restrict__ Wtb = Wt + (size_t)((branch * 4 + ht) * 12) * 8192;

    const int t   = threadIdx.x;
    const int l16 = t & 15;            // A: 16B slot within a row's 256B chunk-span
    const int rg  = t >> 4;            // A: row group 0..31 (row = rg + 32*r)
    const float* xbase = x + (b * NROW + mh * 128) * KC_ + l16 * 4;

    const int bp0 = t >> 7,          bc0 = t & 127;          // B unit t
    const int bp1 = (t + 512) >> 7,  bc1 = t & 127;          // B unit t+512

    float4 av[4];
    short8 bva, bvb;

    auto load_stage = [&](int kc) {
#pragma unroll
        for (int r = 0; r < 4; ++r) {
            const int row = rg + 32 * r;
            if (mh * 128 + row < NROW)
                av[r] = *(const float4*)(xbase + row * KC_ + kc * 64);
            else
                av[r] = make_float4(0.f, 0.f, 0.f, 0.f);
        }
        const unsigned short* wc = Wtb + kc * 8192;
        bva = *(const short8*)(wc + bp0 * 1024 + bc0 * 8);
        bvb = *(const short8*)(wc + bp1 * 1024 + bc1 * 8);
    };

    auto write_stage = [&](int buf) {
#pragma unroll
        for (int r = 0; r < 4; ++r) {
            short4v sv; short2 s;
            s = pk2bf(av[r].x, av[r].y); sv[0] = s.x; sv[1] = s.y;
            s = pk2bf(av[r].z, av[r].w); sv[2] = s.x; sv[3] = s.y;
            const int row = rg + 32 * r;
            *(short4v*)&Alds[buf][((l16 >> 1) * 129 + row) * 8 + (l16 & 1) * 4] = sv;
        }
        *(short8*)&Blds[buf][(bp0 * 129 + bc0) * 8] = bva;
        *(short8*)&Blds[buf][(bp1 * 129 + bc1) * 8] = bvb;
    };

    const int w  = t >> 6;
    const int l  = t & 63;
    const int m  = l & 31;
    const int q  = l >> 5;
    const int sp = w & 1;              // 64-col strip
    const int mp = w >> 1;             // 32-row tile
    const int aoff = (mp * 32 + m) * 8;
    const int boff = (sp * 64 + m) * 8;

    f32x16 acc0 = {}, acc1 = {};

    load_stage(0);
    write_stage(0);
    load_stage(1);
    __syncthreads();

#pragma unroll 1
    for (int kc = 0; kc < 12; ++kc) {
        const int pb = kc & 1;
#pragma unroll
        for (int ks = 0; ks < 4; ++ks) {
            const int base = (ks * 2 + q) * 129 * 8;
            short8 af = *(const short8*)&Alds[pb][base + aoff];
            short8 b0 = *(const short8*)&Blds[pb][base + boff];
            short8 b1 = *(const short8*)&Blds[pb][base + boff + 256];
            acc0 = __builtin_amdgcn_mfma_f32_32x32x16_bf16(af, b0, acc0, 0, 0, 0);
            acc1 = __builtin_amdgcn_mfma_f32_32x32x16_bf16(af, b1, acc1, 0, 0, 0);
        }
        if (kc < 11) write_stage(1 - pb);   // chunk kc+1 -> other buffer
        if (kc < 10) load_stage(kc + 2);    // prefetch chunk kc+2
        __syncthreads();                    // one barrier per chunk
    }

    // relu + sum over rows. C layout: col = lane&31 (m101); lanes l and l^32's
    // 16 regs together cover all 32 rows, order irrelevant for a sum.
    float cs0 = 0.f, cs1 = 0.f;
#pragma unroll
    for (int r = 0; r < 16; ++r) {
        cs0 += fmaxf(acc0[r], 0.f);
        cs1 += fmaxf(acc1[r], 0.f);
    }
    cs0 += __shfl_xor(cs0, 32);
    cs1 += __shfl_xor(cs1, 32);
    if (l < 32) {
        psum[((sp * 2 + 0) * 4 + mp) * 32 + l] = cs0;  // col tile 2sp
        psum[((sp * 2 + 1) * 4 + mp) * 32 + l] = cs1;  // col tile 2sp+1
    }
    __syncthreads();
    if (t < 128) {
        const int ct = t >> 5;
        const int cl = t & 31;
        float v = 0.f;
#pragma unroll
        for (int mp2 = 0; mp2 < 4; ++mp2)
            v += psum[(ct * 4 + mp2) * 32 + cl];
        sbuf[((branch * 2 + mh) * NB + b) * HH + ht * 128 + t] = v;
    }
}

// Kernel 2: out[b,o] = sum_h (s1[b,h]*s2[b,h]) * Wp[h,o] + bp[o]*196^2
__global__ __launch_bounds__(512)
void proj_kernel(const float* __restrict__ sbuf, const float* __restrict__ Wp,
                 const float* __restrict__ bp, float* __restrict__ out) {
    __shared__ float spl[HH];
    __shared__ float red[4][OO];
    const int b = blockIdx.x, t = threadIdx.x;
    {
        const float s1 = sbuf[(0 * NB + b) * HH + t] + sbuf[(1 * NB + b) * HH + t];
        const float s2 = sbuf[(2 * NB + b) * HH + t] + sbuf[(3 * NB + b) * HH + t];
        spl[t] = s1 * s2;
    }
    __syncthreads();
    const int to = t & 127, hq = t >> 7;
    float acc = 0.f;
#pragma unroll 8
    for (int h = hq * 128; h < hq * 128 + 128; ++h)
        acc += spl[h] * Wp[h * OO + to];
    red[hq][to] = acc;
    __syncthreads();
    if (t < OO)
        out[b * OO + t] = red[0][t] + red[1][t] + red[2][t] + red[3][t]
                        + bp[t] * 38416.0f;   // 196*196
}

extern "C" void kernel_launch(void* const* d_in, const int* in_sizes, int n_in,
                              void* d_out, int out_size, void* d_ws, size_t ws_size,
                              hipStream_t stream) {
    const float* x1 = (const float*)d_in[0];
    const float* x2 = (const float*)d_in[1];
    const float* W1 = (const float*)d_in[2];
    const float* W2 = (const float*)d_in[3];
    const float* Wp = (const float*)d_in[4];
    const float* bp = (const float*)d_in[5];
    float* sbuf = (float*)d_ws;                                  // 128 KB
    unsigned short* Wt = (unsigned short*)((char*)d_ws + 131072); // 1.5 MB tiled W

    w_tile<<<96, 256, 0, stream>>>(W1, W2, Wt);
    gemm_relu_rowsum<<<256, 512, 0, stream>>>(x1, x2, Wt, sbuf);
    proj_kernel<<<NB, 512, 0, stream>>>(sbuf, Wp, bp, (float*)d_out);
}